// Round 1
// baseline (1052.253 us; speedup 1.0000x reference)
//
#include <hip/hip_runtime.h>

#define DIN 128
#define HID 128
#define BB  32
#define NN  2048

typedef float  f32x4  __attribute__((ext_vector_type(4)));
typedef __bf16 bf16x8 __attribute__((ext_vector_type(8)));

__device__ __forceinline__ float tanh_fast(float x) {
  // tanh(x) = 1 - 2/(e^{2x}+1); NaN-free for +-inf of exp
  float e = __expf(2.0f * x);
  return 1.0f - 2.0f / (e + 1.0f);
}

// ---------------------------------------------------------------------------
// Kernel 0: W[d][h] (fp32) -> wt[h][d] (bf16), for q,k,v. 3 blocks x 256.
// ---------------------------------------------------------------------------
__global__ __launch_bounds__(256) void wt_kernel(
    const float* __restrict__ Wq, const float* __restrict__ Wk,
    const float* __restrict__ Wv, __bf16* __restrict__ wt) {
  const float* W = (blockIdx.x == 0) ? Wq : (blockIdx.x == 1) ? Wk : Wv;
  __bf16* dst = wt + blockIdx.x * (DIN * HID);
  int t = threadIdx.x;
#pragma unroll
  for (int c = 0; c < 16; ++c) {
    int o = c * 1024 + t * 4;
    int d = o >> 7, h = o & 127;
    f32x4 v = *(const f32x4*)(W + d * HID + h);
    dst[(h + 0) * DIN + d] = (__bf16)v.x;
    dst[(h + 1) * DIN + d] = (__bf16)v.y;
    dst[(h + 2) * DIN + d] = (__bf16)v.z;
    dst[(h + 3) * DIN + d] = (__bf16)v.w;
  }
}

// ---------------------------------------------------------------------------
// Kernel A: q = tanh(xWq+bq), k = tanh(xWk+bk) row-major bf16 [B*N][H];
//           vt = tanh(xWv+bv)^T per batch, bf16 [B][H][N].
// grid = B*N/64 blocks of 256 threads (4 waves; wave w owns rows 16w..16w+15).
// ---------------------------------------------------------------------------
__global__ __launch_bounds__(256) void proj_kernel(
    const float* __restrict__ x, const __bf16* __restrict__ wt,
    const float* __restrict__ bq, const float* __restrict__ bk,
    const float* __restrict__ bv, __bf16* __restrict__ qbf,
    __bf16* __restrict__ kbf, __bf16* __restrict__ vtbf) {
  int tid = threadIdx.x;
  int lane = tid & 63, w = tid >> 6;
  int l15 = lane & 15, quad = lane >> 4;
  long i0 = (long)blockIdx.x * 64;

  // x fragments: bx[nt][ks]: lane holds x[i0+nt*16+l15][ks*32+quad*8 .. +7]
  bf16x8 bx[4][4];
#pragma unroll
  for (int nt = 0; nt < 4; ++nt) {
    const float* xp = x + (i0 + nt * 16 + l15) * DIN;
#pragma unroll
    for (int ks = 0; ks < 4; ++ks) {
      int d0 = ks * 32 + quad * 8;
      f32x4 a = *(const f32x4*)(xp + d0);
      f32x4 b = *(const f32x4*)(xp + d0 + 4);
      bf16x8 f;
      f[0] = (__bf16)a.x; f[1] = (__bf16)a.y; f[2] = (__bf16)a.z; f[3] = (__bf16)a.w;
      f[4] = (__bf16)b.x; f[5] = (__bf16)b.y; f[6] = (__bf16)b.z; f[7] = (__bf16)b.w;
      bx[nt][ks] = f;
    }
  }

  // q and k: D[i][h] = sum_d x[i][d] * W[d][h]; A = x frag, B = wt[h][d]
#pragma unroll
  for (int p = 0; p < 2; ++p) {
    const __bf16* wtp = wt + p * DIN * HID;       // 0=q, 1=k
    const float* bias = (p == 0) ? bq : bk;
    __bf16* outp = (p == 0) ? qbf : kbf;
#pragma unroll
    for (int nt = 0; nt < 8; ++nt) {
      int h0 = nt * 16 + l15;
      f32x4 acc = {0.f, 0.f, 0.f, 0.f};
#pragma unroll
      for (int ks = 0; ks < 4; ++ks) {
        bf16x8 wf = *(const bf16x8*)(wtp + (long)h0 * DIN + ks * 32 + quad * 8);
        acc = __builtin_amdgcn_mfma_f32_16x16x32_bf16(bx[w][ks], wf, acc, 0, 0, 0);
      }
      float bcol = bias[h0];
      long rowb = i0 + w * 16 + quad * 4;
#pragma unroll
      for (int r = 0; r < 4; ++r) {
        float val = tanh_fast(acc[r] + bcol);
        outp[(rowb + r) * HID + h0] = (__bf16)val;
      }
    }
  }

  // vt: D[h][n] = sum_d W[d][h] * x[n][d]; A = wt frag, B = x frag
  {
    const __bf16* wtp = wt + 2 * DIN * HID;
    long bb = i0 >> 11;            // batch index
    int nloc = (int)(i0 & 2047);   // row within batch
    long vbase = bb * (long)HID * NN;
#pragma unroll
    for (int s = 0; s < 2; ++s) {
      int hb = w * 32 + s * 16;
      bf16x8 af[4];
#pragma unroll
      for (int ks = 0; ks < 4; ++ks)
        af[ks] = *(const bf16x8*)(wtp + (long)(hb + l15) * DIN + ks * 32 + quad * 8);
      float bvr[4];
#pragma unroll
      for (int r = 0; r < 4; ++r) bvr[r] = bv[hb + quad * 4 + r];
#pragma unroll
      for (int nt = 0; nt < 4; ++nt) {
        f32x4 acc = {0.f, 0.f, 0.f, 0.f};
#pragma unroll
        for (int ks = 0; ks < 4; ++ks)
          acc = __builtin_amdgcn_mfma_f32_16x16x32_bf16(af[ks], bx[nt][ks], acc, 0, 0, 0);
        int hrow = hb + quad * 4;
        int ncol = nloc + nt * 16 + l15;
#pragma unroll
        for (int r = 0; r < 4; ++r) {
          float val = tanh_fast(acc[r] + bvr[r]);
          vtbf[vbase + (long)(hrow + r) * NN + ncol] = (__bf16)val;
        }
      }
    }
  }
}

// ---------------------------------------------------------------------------
// Kernel B: flash attention. grid = B * (N/64); block = 256 (4 waves).
// Wave w owns q rows i0+16w..+15. j-loop over 32 tiles of 64 keys.
// ---------------------------------------------------------------------------
#define KSTR 136   // Ks row stride (elems): 272 B, 16B-aligned, bank-safe
#define VSTR 72    // Vts row stride: 144 B
#define PSTR 72    // P row stride

__global__ __launch_bounds__(256) void attn_kernel(
    const __bf16* __restrict__ qbf, const __bf16* __restrict__ kbf,
    const __bf16* __restrict__ vtbf, const float* __restrict__ mask,
    float* __restrict__ out) {
  __shared__ __bf16 Ks[64 * KSTR];
  __shared__ __bf16 Vts[128 * VSTR];
  __shared__ __bf16 Pl[4 * 16 * PSTR];

  int tid = threadIdx.x;
  int lane = tid & 63, w = tid >> 6;
  int l15 = lane & 15, quad = lane >> 4;
  int bid = blockIdx.x;
  int b = bid >> 5;
  int i0 = (bid & 31) * 64;
  long kvbase = (long)b * NN * HID;

  bf16x8 qf[4];
  {
    const __bf16* qp = qbf + kvbase + (long)(i0 + w * 16 + l15) * HID;
#pragma unroll
    for (int ks = 0; ks < 4; ++ks)
      qf[ks] = *(const bf16x8*)(qp + ks * 32 + quad * 8);
  }

  f32x4 O[8];
#pragma unroll
  for (int i = 0; i < 8; ++i) O[i] = (f32x4){0.f, 0.f, 0.f, 0.f};
  float mrow[4], lrow[4];
#pragma unroll
  for (int r = 0; r < 4; ++r) { mrow[r] = -1e30f; lrow[r] = 0.0f; }

  const float* maskrow =
      mask + ((long)b * NN + (i0 + w * 16 + quad * 4)) * NN;
  __bf16* Pw = Pl + w * 16 * PSTR;

  for (int jt = 0; jt < 32; ++jt) {
    int j0 = jt * 64;
    // ---- stage K tile [64][128] and Vt tile [128][64] into padded LDS
    {
      const __bf16* ksrc = kbf + kvbase + (long)j0 * HID;
#pragma unroll
      for (int pass = 0; pass < 4; ++pass) {
        int o = pass * 2048 + tid * 8;
        int row = o >> 7, col = o & 127;
        bf16x8 v = *(const bf16x8*)(ksrc + (long)row * HID + col);
        *(bf16x8*)(Ks + row * KSTR + col) = v;
      }
      const __bf16* vsrc = vtbf + (long)b * HID * NN + j0;
#pragma unroll
      for (int pass = 0; pass < 4; ++pass) {
        int o = pass * 2048 + tid * 8;
        int h = o >> 6, c = o & 63;
        bf16x8 v = *(const bf16x8*)(vsrc + (long)h * NN + c);
        *(bf16x8*)(Vts + h * VSTR + c) = v;
      }
    }
    // mask values at this wave's C-layout positions (coalesced 64B segments)
    float mv[4][4];
#pragma unroll
    for (int t = 0; t < 4; ++t)
#pragma unroll
      for (int r = 0; r < 4; ++r)
        mv[t][r] = maskrow[(long)r * NN + j0 + t * 16 + l15];
    __syncthreads();

    // ---- S = Q K^T  (wave: 16 rows x 64 cols)
    f32x4 S[4];
#pragma unroll
    for (int t = 0; t < 4; ++t) {
      f32x4 acc = {0.f, 0.f, 0.f, 0.f};
      const __bf16* kp = Ks + (t * 16 + l15) * KSTR;
#pragma unroll
      for (int ks = 0; ks < 4; ++ks) {
        bf16x8 kf = *(const bf16x8*)(kp + ks * 32 + quad * 8);
        acc = __builtin_amdgcn_mfma_f32_16x16x32_bf16(qf[ks], kf, acc, 0, 0, 0);
      }
      S[t] = acc;
    }

    // ---- masked online softmax (rows = quad*4 + r)
    float p[4][4], alpha[4];
#pragma unroll
    for (int r = 0; r < 4; ++r) {
      float s0 = (mv[0][r] != 0.0f) ? S[0][r] : -1e30f;
      float s1 = (mv[1][r] != 0.0f) ? S[1][r] : -1e30f;
      float s2 = (mv[2][r] != 0.0f) ? S[2][r] : -1e30f;
      float s3 = (mv[3][r] != 0.0f) ? S[3][r] : -1e30f;
      float mx = fmaxf(fmaxf(s0, s1), fmaxf(s2, s3));
      mx = fmaxf(mx, __shfl_xor(mx, 1));
      mx = fmaxf(mx, __shfl_xor(mx, 2));
      mx = fmaxf(mx, __shfl_xor(mx, 4));
      mx = fmaxf(mx, __shfl_xor(mx, 8));
      float mnew = fmaxf(mrow[r], mx);
      alpha[r] = __expf(mrow[r] - mnew);
      float p0 = __expf(s0 - mnew), p1 = __expf(s1 - mnew);
      float p2 = __expf(s2 - mnew), p3 = __expf(s3 - mnew);
      p[0][r] = p0; p[1][r] = p1; p[2][r] = p2; p[3][r] = p3;
      float rs = p0 + p1 + p2 + p3;
      rs += __shfl_xor(rs, 1);
      rs += __shfl_xor(rs, 2);
      rs += __shfl_xor(rs, 4);
      rs += __shfl_xor(rs, 8);
      lrow[r] = lrow[r] * alpha[r] + rs;
      mrow[r] = mnew;
    }
#pragma unroll
    for (int nt = 0; nt < 8; ++nt)
#pragma unroll
      for (int r = 0; r < 4; ++r) O[nt][r] *= alpha[r];

    // ---- P: C-layout -> LDS -> A-layout (wave-private, no barrier needed)
#pragma unroll
    for (int t = 0; t < 4; ++t)
#pragma unroll
      for (int r = 0; r < 4; ++r)
        Pw[(quad * 4 + r) * PSTR + t * 16 + l15] = (__bf16)p[t][r];
    bf16x8 pf[2];
#pragma unroll
    for (int js = 0; js < 2; ++js)
      pf[js] = *(const bf16x8*)(Pw + l15 * PSTR + js * 32 + quad * 8);

    // ---- O += P @ V
#pragma unroll
    for (int nt = 0; nt < 8; ++nt) {
      const __bf16* vp = Vts + (nt * 16 + l15) * VSTR;
#pragma unroll
      for (int js = 0; js < 2; ++js) {
        bf16x8 vf = *(const bf16x8*)(vp + js * 32 + quad * 8);
        O[nt] = __builtin_amdgcn_mfma_f32_16x16x32_bf16(pf[js], vf, O[nt], 0, 0, 0);
      }
    }
    __syncthreads();
  }

  // ---- epilogue: out = O / l  (fp32 stores, 64B segments)
  {
    long rowb = (long)b * NN + i0 + w * 16 + quad * 4;
#pragma unroll
    for (int r = 0; r < 4; ++r) {
      float inv = 1.0f / lrow[r];
      float* op = out + (rowb + r) * HID;
#pragma unroll
      for (int nt = 0; nt < 8; ++nt) op[nt * 16 + l15] = O[nt][r] * inv;
    }
  }
}

// ---------------------------------------------------------------------------
extern "C" void kernel_launch(void* const* d_in, const int* in_sizes, int n_in,
                              void* d_out, int out_size, void* d_ws, size_t ws_size,
                              hipStream_t stream) {
  const float* x    = (const float*)d_in[0];
  const float* mask = (const float*)d_in[1];
  const float* Wv   = (const float*)d_in[2];
  const float* bv   = (const float*)d_in[3];
  const float* Wk   = (const float*)d_in[4];
  const float* bk   = (const float*)d_in[5];
  const float* Wq   = (const float*)d_in[6];
  const float* bq   = (const float*)d_in[7];
  float* out = (float*)d_out;

  __bf16* ws = (__bf16*)d_ws;
  __bf16* wt   = ws;                      // 3 * 128*128
  __bf16* qbf  = ws + 3 * DIN * HID;      // B*N*H
  __bf16* kbf  = qbf + (long)BB * NN * HID;
  __bf16* vtbf = kbf + (long)BB * NN * HID;

  wt_kernel<<<3, 256, 0, stream>>>(Wq, Wk, Wv, wt);
  proj_kernel<<<BB * NN / 64, 256, 0, stream>>>(x, wt, bq, bk, bv, qbf, kbf, vtbf);
  attn_kernel<<<BB * (NN / 64), 256, 0, stream>>>(qbf, kbf, vtbf, mask, out);
}

// Round 2
// 842.907 us; speedup vs baseline: 1.2484x; 1.2484x over previous
//
#include <hip/hip_runtime.h>

#define DIN 128
#define HID 128
#define BB  32
#define NN  2048
#define LOG2E 1.44269504088896340736f

typedef float  f32x4   __attribute__((ext_vector_type(4)));
typedef __bf16 bf16x4v __attribute__((ext_vector_type(4)));
typedef __bf16 bf16x8  __attribute__((ext_vector_type(8)));

__device__ __forceinline__ float tanh_fast(float x) {
  // tanh(x) = 1 - 2/(e^{2x}+1); NaN-free for +-inf of exp
  float e = __expf(2.0f * x);
  return 1.0f - 2.0f / (e + 1.0f);
}

// ---------------------------------------------------------------------------
// Kernel 0: W[d][h] (fp32) -> wt[h][d] (bf16), for q,k,v. 3 blocks x 256.
// ---------------------------------------------------------------------------
__global__ __launch_bounds__(256) void wt_kernel(
    const float* __restrict__ Wq, const float* __restrict__ Wk,
    const float* __restrict__ Wv, __bf16* __restrict__ wt) {
  const float* W = (blockIdx.x == 0) ? Wq : (blockIdx.x == 1) ? Wk : Wv;
  __bf16* dst = wt + blockIdx.x * (DIN * HID);
  int t = threadIdx.x;
#pragma unroll
  for (int c = 0; c < 16; ++c) {
    int o = c * 1024 + t * 4;
    int d = o >> 7, h = o & 127;
    f32x4 v = *(const f32x4*)(W + d * HID + h);
    dst[(h + 0) * DIN + d] = (__bf16)v.x;
    dst[(h + 1) * DIN + d] = (__bf16)v.y;
    dst[(h + 2) * DIN + d] = (__bf16)v.z;
    dst[(h + 3) * DIN + d] = (__bf16)v.w;
  }
}

// ---------------------------------------------------------------------------
// Kernel A: q = tanh(xWq+bq)*LOG2E, k = tanh(xWk+bk) row-major bf16 [B*N][H];
//           vt = tanh(xWv+bv)^T per batch, bf16 [B][H][N].
// grid = B*N/64 blocks of 256 threads (4 waves; wave w owns rows 16w..16w+15).
// ---------------------------------------------------------------------------
__global__ __launch_bounds__(256) void proj_kernel(
    const float* __restrict__ x, const __bf16* __restrict__ wt,
    const float* __restrict__ bq, const float* __restrict__ bk,
    const float* __restrict__ bv, __bf16* __restrict__ qbf,
    __bf16* __restrict__ kbf, __bf16* __restrict__ vtbf) {
  int tid = threadIdx.x;
  int lane = tid & 63, w = tid >> 6;
  int l15 = lane & 15, quad = lane >> 4;
  long i0 = (long)blockIdx.x * 64;

  // x fragments: bx[nt][ks]: lane holds x[i0+nt*16+l15][ks*32+quad*8 .. +7]
  bf16x8 bx[4][4];
#pragma unroll
  for (int nt = 0; nt < 4; ++nt) {
    const float* xp = x + (i0 + nt * 16 + l15) * DIN;
#pragma unroll
    for (int ks = 0; ks < 4; ++ks) {
      int d0 = ks * 32 + quad * 8;
      f32x4 a = *(const f32x4*)(xp + d0);
      f32x4 b = *(const f32x4*)(xp + d0 + 4);
      bf16x8 f;
      f[0] = (__bf16)a.x; f[1] = (__bf16)a.y; f[2] = (__bf16)a.z; f[3] = (__bf16)a.w;
      f[4] = (__bf16)b.x; f[5] = (__bf16)b.y; f[6] = (__bf16)b.z; f[7] = (__bf16)b.w;
      bx[nt][ks] = f;
    }
  }

  // q and k: D[i][h] = sum_d x[i][d] * W[d][h]; A = x frag, B = wt[h][d]
#pragma unroll
  for (int p = 0; p < 2; ++p) {
    const __bf16* wtp = wt + p * DIN * HID;       // 0=q, 1=k
    const float* bias = (p == 0) ? bq : bk;
    __bf16* outp = (p == 0) ? qbf : kbf;
#pragma unroll
    for (int nt = 0; nt < 8; ++nt) {
      int h0 = nt * 16 + l15;
      f32x4 acc = {0.f, 0.f, 0.f, 0.f};
#pragma unroll
      for (int ks = 0; ks < 4; ++ks) {
        bf16x8 wf = *(const bf16x8*)(wtp + (long)h0 * DIN + ks * 32 + quad * 8);
        acc = __builtin_amdgcn_mfma_f32_16x16x32_bf16(bx[w][ks], wf, acc, 0, 0, 0);
      }
      float bcol = bias[h0];
      long rowb = i0 + w * 16 + quad * 4;
#pragma unroll
      for (int r = 0; r < 4; ++r) {
        float val = tanh_fast(acc[r] + bcol);
        if (p == 0) val *= LOG2E;   // fold log2(e) into q for exp2 softmax
        outp[(rowb + r) * HID + h0] = (__bf16)val;
      }
    }
  }

  // vt: D[h][n] = sum_d W[d][h] * x[n][d]; A = wt frag, B = x frag
  {
    const __bf16* wtp = wt + 2 * DIN * HID;
    long bb = i0 >> 11;            // batch index
    int nloc = (int)(i0 & 2047);   // row within batch
    long vbase = bb * (long)HID * NN;
#pragma unroll
    for (int s = 0; s < 2; ++s) {
      int hb = w * 32 + s * 16;
      bf16x8 af[4];
#pragma unroll
      for (int ks = 0; ks < 4; ++ks)
        af[ks] = *(const bf16x8*)(wtp + (long)(hb + l15) * DIN + ks * 32 + quad * 8);
      float bvr[4];
#pragma unroll
      for (int r = 0; r < 4; ++r) bvr[r] = bv[hb + quad * 4 + r];
#pragma unroll
      for (int nt = 0; nt < 4; ++nt) {
        f32x4 acc = {0.f, 0.f, 0.f, 0.f};
#pragma unroll
        for (int ks = 0; ks < 4; ++ks)
          acc = __builtin_amdgcn_mfma_f32_16x16x32_bf16(af[ks], bx[nt][ks], acc, 0, 0, 0);
        int hrow = hb + quad * 4;
        int ncol = nloc + nt * 16 + l15;
#pragma unroll
        for (int r = 0; r < 4; ++r) {
          float val = tanh_fast(acc[r] + bvr[r]);
          vtbf[vbase + (long)(hrow + r) * NN + ncol] = (__bf16)val;
        }
      }
    }
  }
}

// ---------------------------------------------------------------------------
// Kernel B: flash attention, software-pipelined.
// grid = 512 blocks x 512 threads (8 waves). Block owns 128 q-rows.
// Wave w owns q rows i0+16w..+15 (i = lane&15 in the transposed-S layout).
// K-loop: 32 tiles of 64 keys; K/V/mask for tile j+1 register-prefetched
// during compute of tile j, staged to (single-buffered) LDS after barrier.
// ---------------------------------------------------------------------------
#define KSTR 136   // Ks row stride: 272 B, 16B-aligned
#define VSTR 72    // Vts row stride: 144 B, 16B-aligned
#define PSTR 72    // P row stride: 144 B, 16B-aligned

__global__ __launch_bounds__(512, 4) void attn_kernel(
    const __bf16* __restrict__ qbf, const __bf16* __restrict__ kbf,
    const __bf16* __restrict__ vtbf, const float* __restrict__ mask,
    float* __restrict__ out) {
  __shared__ __bf16 Ks[64 * KSTR];       // 17408 B
  __shared__ __bf16 Vts[128 * VSTR];     // 18432 B
  __shared__ __bf16 Pl[8 * 16 * PSTR];   // 18432 B  (total 54272 B)

  const int tid = threadIdx.x;
  const int lane = tid & 63, w = tid >> 6;
  const int l15 = lane & 15, quad = lane >> 4;
  // XCD swizzle: 64 consecutive virtual blocks (= 4 whole batches) per XCD
  const int bid = blockIdx.x;
  const int vb = (bid >> 3) | ((bid & 7) << 6);
  const int b = vb >> 4;
  const int i0 = (vb & 15) * 128;
  const long kvbase = (long)b * NN * HID;

  // Q fragment (B operand of S^T): lane l15 = q-row, quad*8+e = k-dim
  bf16x8 qf[4];
  {
    const __bf16* qp = qbf + kvbase + (long)(i0 + w * 16 + l15) * HID + quad * 8;
#pragma unroll
    for (int ks = 0; ks < 4; ++ks) qf[ks] = *(const bf16x8*)(qp + ks * 32);
  }

  // staging geometry (512 threads, 2 passes per tile for each of K and Vt)
  const int krow = tid >> 4, kcol = (tid & 15) * 8;
  const int vrow = tid >> 3, vcol = (tid & 7) * 8;
  const __bf16* kg = kbf + kvbase + (long)krow * HID + kcol;
  const __bf16* vg = vtbf + (long)b * HID * NN + (long)vrow * NN + vcol;
  __bf16* ksd0 = Ks + krow * KSTR + kcol;
  __bf16* ksd1 = Ks + (krow + 32) * KSTR + kcol;
  __bf16* vsd0 = Vts + vrow * VSTR + vcol;
  __bf16* vsd1 = Vts + (vrow + 64) * VSTR + vcol;
  // mask: lane reads row i = i0+w*16+l15, 4 consecutive cols at quad*4
  const float* mp = mask + ((long)b * NN + (i0 + w * 16 + l15)) * NN + quad * 4;
  __bf16* Pw = Pl + w * 16 * PSTR;

  f32x4 O[8];
#pragma unroll
  for (int i = 0; i < 8; ++i) O[i] = (f32x4){0.f, 0.f, 0.f, 0.f};
  float mrow = -1e30f, lrow = 0.0f;   // per q-row i = l15 (replicated over quads)

  // ---- prologue: load + stage tile 0
  bf16x8 kr0 = *(const bf16x8*)(kg);
  bf16x8 kr1 = *(const bf16x8*)(kg + 32 * HID);
  bf16x8 vr0 = *(const bf16x8*)(vg);
  bf16x8 vr1 = *(const bf16x8*)(vg + (long)64 * NN);
  f32x4 mr[4];
#pragma unroll
  for (int t = 0; t < 4; ++t) mr[t] = *(const f32x4*)(mp + t * 16);
  *(bf16x8*)ksd0 = kr0; *(bf16x8*)ksd1 = kr1;
  *(bf16x8*)vsd0 = vr0; *(bf16x8*)vsd1 = vr1;
  unsigned mbits;
  {
    float mb = 0.f;
#pragma unroll
    for (int t = 0; t < 4; ++t)
#pragma unroll
      for (int r = 0; r < 4; ++r)
        mb = fmaf(mr[t][r], (float)(1u << (t * 4 + r)), mb);  // mask is exactly 0/1
    mbits = (unsigned)mb;
  }
  __syncthreads();

  for (int jt = 0; jt < 32; ++jt) {
    const int jn = (jt < 31) ? jt + 1 : 31;   // redundant reload on last iter
    // ---- issue prefetch for tile jn (in flight across the whole compute phase)
    {
      const __bf16* kgn = kg + (long)jn * 64 * HID;
      kr0 = *(const bf16x8*)(kgn);
      kr1 = *(const bf16x8*)(kgn + 32 * HID);
      const __bf16* vgn = vg + jn * 64;
      vr0 = *(const bf16x8*)(vgn);
      vr1 = *(const bf16x8*)(vgn + (long)64 * NN);
#pragma unroll
      for (int t = 0; t < 4; ++t) mr[t] = *(const f32x4*)(mp + jn * 64 + t * 16);
    }

    // ---- S^T = K Q^T : rows = keys (quad*4+r within subtile t), cols = q (l15)
    f32x4 pt[4];
#pragma unroll
    for (int t = 0; t < 4; ++t) {
      f32x4 acc = {0.f, 0.f, 0.f, 0.f};
      const __bf16* kp = Ks + (t * 16 + l15) * KSTR + quad * 8;
#pragma unroll
      for (int ks = 0; ks < 4; ++ks) {
        bf16x8 kf = *(const bf16x8*)(kp + ks * 32);
        acc = __builtin_amdgcn_mfma_f32_16x16x32_bf16(kf, qf[ks], acc, 0, 0, 0);
      }
      pt[t] = acc;
    }

    // ---- masked online softmax (log2 domain; q pre-scaled by log2 e)
    float tmx = -1e30f;
#pragma unroll
    for (int t = 0; t < 4; ++t)
#pragma unroll
      for (int r = 0; r < 4; ++r) {
        float s = ((mbits >> (t * 4 + r)) & 1u) ? pt[t][r] : -1e30f;
        pt[t][r] = s;
        tmx = fmaxf(tmx, s);
      }
    tmx = fmaxf(tmx, __shfl_xor(tmx, 16));
    tmx = fmaxf(tmx, __shfl_xor(tmx, 32));
    const float mnew = fmaxf(mrow, tmx);
    const float alpha = exp2f(mrow - mnew);
    float rs = 0.0f;
#pragma unroll
    for (int t = 0; t < 4; ++t)
#pragma unroll
      for (int r = 0; r < 4; ++r) {
        float p = exp2f(pt[t][r] - mnew);
        pt[t][r] = p;
        rs += p;
      }
    rs += __shfl_xor(rs, 16);
    rs += __shfl_xor(rs, 32);
    lrow = lrow * alpha + rs;
    mrow = mnew;

    // ---- rescale O (O rows are i = quad*4+r; alpha lives at lane l15 = i)
    float ar[4];
#pragma unroll
    for (int r = 0; r < 4; ++r) ar[r] = __shfl(alpha, (quad << 2) + r);
#pragma unroll
    for (int nt = 0; nt < 8; ++nt)
#pragma unroll
      for (int r = 0; r < 4; ++r) O[nt][r] *= ar[r];

    // ---- P: S^T layout -> LDS [i][j] -> A-layout (wave-private, b64 writes)
#pragma unroll
    for (int t = 0; t < 4; ++t) {
      bf16x4v pb;
#pragma unroll
      for (int r = 0; r < 4; ++r) pb[r] = (__bf16)pt[t][r];
      *(bf16x4v*)(Pw + l15 * PSTR + t * 16 + quad * 4) = pb;
    }
    const bf16x8 pf0 = *(const bf16x8*)(Pw + l15 * PSTR + quad * 8);
    const bf16x8 pf1 = *(const bf16x8*)(Pw + l15 * PSTR + 32 + quad * 8);

    // ---- O += P V
#pragma unroll
    for (int nt = 0; nt < 8; ++nt) {
      const __bf16* vp = Vts + (nt * 16 + l15) * VSTR + quad * 8;
      bf16x8 vf0 = *(const bf16x8*)(vp);
      bf16x8 vf1 = *(const bf16x8*)(vp + 32);
      O[nt] = __builtin_amdgcn_mfma_f32_16x16x32_bf16(pf0, vf0, O[nt], 0, 0, 0);
      O[nt] = __builtin_amdgcn_mfma_f32_16x16x32_bf16(pf1, vf1, O[nt], 0, 0, 0);
    }

    __syncthreads();   // all waves done reading tile jt from LDS
    // ---- stage prefetched tile jn into LDS; compress its mask
    *(bf16x8*)ksd0 = kr0; *(bf16x8*)ksd1 = kr1;
    *(bf16x8*)vsd0 = vr0; *(bf16x8*)vsd1 = vr1;
    {
      float mb = 0.f;
#pragma unroll
      for (int t = 0; t < 4; ++t)
#pragma unroll
        for (int r = 0; r < 4; ++r)
          mb = fmaf(mr[t][r], (float)(1u << (t * 4 + r)), mb);
      mbits = (unsigned)mb;
    }
    __syncthreads();   // tile jn visible to all waves
  }

  // ---- epilogue: out[i][h] = O / l
  const float inv = 1.0f / lrow;
  float il[4];
#pragma unroll
  for (int r = 0; r < 4; ++r) il[r] = __shfl(inv, (quad << 2) + r);
  const long rowb = (long)b * NN + i0 + w * 16 + quad * 4;
#pragma unroll
  for (int r = 0; r < 4; ++r) {
    float* op = out + (rowb + r) * HID;
#pragma unroll
    for (int nt = 0; nt < 8; ++nt) op[nt * 16 + l15] = O[nt][r] * il[r];
  }
}

// ---------------------------------------------------------------------------
extern "C" void kernel_launch(void* const* d_in, const int* in_sizes, int n_in,
                              void* d_out, int out_size, void* d_ws, size_t ws_size,
                              hipStream_t stream) {
  const float* x    = (const float*)d_in[0];
  const float* mask = (const float*)d_in[1];
  const float* Wv   = (const float*)d_in[2];
  const float* bv   = (const float*)d_in[3];
  const float* Wk   = (const float*)d_in[4];
  const float* bk   = (const float*)d_in[5];
  const float* Wq   = (const float*)d_in[6];
  const float* bq   = (const float*)d_in[7];
  float* out = (float*)d_out;

  __bf16* ws = (__bf16*)d_ws;
  __bf16* wt   = ws;                      // 3 * 128*128
  __bf16* qbf  = ws + 3 * DIN * HID;      // B*N*H
  __bf16* kbf  = qbf + (long)BB * NN * HID;
  __bf16* vtbf = kbf + (long)BB * NN * HID;

  wt_kernel<<<3, 256, 0, stream>>>(Wq, Wk, Wv, wt);
  proj_kernel<<<BB * NN / 64, 256, 0, stream>>>(x, wt, bq, bk, bv, qbf, kbf, vtbf);
  attn_kernel<<<512, 512, 0, stream>>>(qbf, kbf, vtbf, mask, out);
}